// Round 1
// baseline (683.755 us; speedup 1.0000x reference)
//
#include <hip/hip_runtime.h>

// Resample2d (Flownet2-style) bilinear warp.
// feature: [B,C,H,W] fp32, flow: [B,2,H,W] fp32, out: [B,C,H,W] fp32.
// One thread per output pixel (b,y,x): weights/indices computed once,
// inner loop over C=64 channels (same taps for every channel).

#define Bv 2
#define Cv 64
#define Hv 512
#define Wv 896

__global__ __launch_bounds__(256) void resample2d_kernel(
    const float* __restrict__ feature,
    const float* __restrict__ flow,
    float* __restrict__ out) {
    const int x = blockIdx.x * blockDim.x + threadIdx.x;
    const int y = blockIdx.y;
    const int b = blockIdx.z;
    if (x >= Wv) return;

    const int HW = Hv * Wv;
    const int pix = y * Wv + x;

    const float* flb = flow + (size_t)b * 2 * HW;
    const float u = flb[pix];          // x-displacement
    const float v = flb[HW + pix];     // y-displacement

    const float gx = u + (float)x;
    const float gy = v + (float)y;
    const float x0f = floorf(gx);
    const float y0f = floorf(gy);
    const float wx = gx - x0f;
    const float wy = gy - y0f;
    const int x0 = (int)x0f;
    const int y0 = (int)y0f;
    const int x1 = x0 + 1;
    const int y1 = y0 + 1;

    const bool vx0 = (x0 >= 0) & (x0 < Wv);
    const bool vx1 = (x1 >= 0) & (x1 < Wv);
    const bool vy0 = (y0 >= 0) & (y0 < Hv);
    const bool vy1 = (y1 >= 0) & (y1 < Hv);

    const int cx0 = min(max(x0, 0), Wv - 1);
    const int cx1 = min(max(x1, 0), Wv - 1);
    const int cy0 = min(max(y0, 0), Hv - 1);
    const int cy1 = min(max(y1, 0), Hv - 1);

    // Fold validity into the weights (reference zeroes the weight, clips the index).
    const float w00 = (1.0f - wx) * (1.0f - wy) * ((vx0 & vy0) ? 1.0f : 0.0f);
    const float w10 = wx * (1.0f - wy) * ((vx1 & vy0) ? 1.0f : 0.0f);
    const float w01 = (1.0f - wx) * wy * ((vx0 & vy1) ? 1.0f : 0.0f);
    const float w11 = wx * wy * ((vx1 & vy1) ? 1.0f : 0.0f);

    const int i00 = cy0 * Wv + cx0;
    const int i10 = cy0 * Wv + cx1;
    const int i01 = cy1 * Wv + cx0;
    const int i11 = cy1 * Wv + cx1;

    const float* __restrict__ fb = feature + (size_t)b * Cv * HW;
    float* __restrict__ ob = out + (size_t)b * Cv * HW + pix;

#pragma unroll 4
    for (int c = 0; c < Cv; ++c) {
        const float* __restrict__ f = fb + c * HW;
        const float r = f[i00] * w00 + f[i10] * w10 + f[i01] * w01 + f[i11] * w11;
        ob[(size_t)c * HW] = r;
    }
}

extern "C" void kernel_launch(void* const* d_in, const int* in_sizes, int n_in,
                              void* d_out, int out_size, void* d_ws, size_t ws_size,
                              hipStream_t stream) {
    const float* feature = (const float*)d_in[0];
    const float* flow    = (const float*)d_in[1];
    float* out           = (float*)d_out;

    dim3 block(256, 1, 1);
    dim3 grid((Wv + 255) / 256, Hv, Bv);
    resample2d_kernel<<<grid, block, 0, stream>>>(feature, flow, out);
}

// Round 2
// 637.708 us; speedup vs baseline: 1.0722x; 1.0722x over previous
//
#include <hip/hip_runtime.h>

// Resample2d (Flownet2-style) bilinear warp.
// feature: [B,C,H,W] fp32, flow: [B,2,H,W] fp32, out: [B,C,H,W] fp32.
//
// Latency-bound fix (R1): thread = pixel but only CPG=8 channels per thread;
// channel groups spread across gridDim.z (8x more waves for TLP). All 32 tap
// loads (8 channels x 4 taps) are issued into a register array before any
// use, so they are in flight simultaneously (ILP).

#define Bv 2
#define Cv 64
#define Hv 512
#define Wv 896

#define CPG 8                 // channels per thread
#define NCG (Cv / CPG)        // channel groups = 8

__global__ __launch_bounds__(256) void resample2d_kernel(
    const float* __restrict__ feature,
    const float* __restrict__ flow,
    float* __restrict__ out) {
    const int x  = blockIdx.x * blockDim.x + threadIdx.x;
    const int y  = blockIdx.y;
    const int zb = blockIdx.z;
    const int b  = zb / NCG;
    const int c0 = (zb % NCG) * CPG;
    if (x >= Wv) return;

    const int HW  = Hv * Wv;
    const int pix = y * Wv + x;

    const float* flb = flow + (size_t)b * 2 * HW;
    const float u = flb[pix];          // x-displacement
    const float v = flb[HW + pix];     // y-displacement

    const float gx = u + (float)x;
    const float gy = v + (float)y;
    const float x0f = floorf(gx);
    const float y0f = floorf(gy);
    const float wx = gx - x0f;
    const float wy = gy - y0f;
    const int x0 = (int)x0f;
    const int y0 = (int)y0f;
    const int x1 = x0 + 1;
    const int y1 = y0 + 1;

    const bool vx0 = (x0 >= 0) & (x0 < Wv);
    const bool vx1 = (x1 >= 0) & (x1 < Wv);
    const bool vy0 = (y0 >= 0) & (y0 < Hv);
    const bool vy1 = (y1 >= 0) & (y1 < Hv);

    const int cx0 = min(max(x0, 0), Wv - 1);
    const int cx1 = min(max(x1, 0), Wv - 1);
    const int cy0 = min(max(y0, 0), Hv - 1);
    const int cy1 = min(max(y1, 0), Hv - 1);

    // Fold validity into the weights (reference zeroes the weight, clips the index).
    const float w00 = (1.0f - wx) * (1.0f - wy) * ((vx0 & vy0) ? 1.0f : 0.0f);
    const float w10 = wx * (1.0f - wy) * ((vx1 & vy0) ? 1.0f : 0.0f);
    const float w01 = (1.0f - wx) * wy * ((vx0 & vy1) ? 1.0f : 0.0f);
    const float w11 = wx * wy * ((vx1 & vy1) ? 1.0f : 0.0f);

    const int i00 = cy0 * Wv + cx0;
    const int i10 = cy0 * Wv + cx1;
    const int i01 = cy1 * Wv + cx0;
    const int i11 = cy1 * Wv + cx1;

    const float* __restrict__ fb = feature + (size_t)b * Cv * HW + (size_t)c0 * HW;
    float* __restrict__ ob = out + (size_t)b * Cv * HW + (size_t)c0 * HW + pix;

    // Phase 1: issue ALL 32 tap loads before any consumption (deep vmcnt queue).
    float t00[CPG], t10[CPG], t01[CPG], t11[CPG];
#pragma unroll
    for (int j = 0; j < CPG; ++j) {
        const float* __restrict__ f = fb + (size_t)j * HW;
        t00[j] = f[i00];
        t10[j] = f[i10];
        t01[j] = f[i01];
        t11[j] = f[i11];
    }

    // Phase 2: combine and store.
#pragma unroll
    for (int j = 0; j < CPG; ++j) {
        ob[(size_t)j * HW] = t00[j] * w00 + t10[j] * w10 + t01[j] * w01 + t11[j] * w11;
    }
}

extern "C" void kernel_launch(void* const* d_in, const int* in_sizes, int n_in,
                              void* d_out, int out_size, void* d_ws, size_t ws_size,
                              hipStream_t stream) {
    const float* feature = (const float*)d_in[0];
    const float* flow    = (const float*)d_in[1];
    float* out           = (float*)d_out;

    dim3 block(256, 1, 1);
    dim3 grid((Wv + 255) / 256, Hv, Bv * NCG);
    resample2d_kernel<<<grid, block, 0, stream>>>(feature, flow, out);
}